// Round 3
// baseline (2890.646 us; speedup 1.0000x reference)
//
#include <hip/hip_runtime.h>
#include <hip/hip_bf16.h>

// MHAGCN: x(4096,6,1024) -> out(4096,6,256).
// R3: dtype-robust. A probe kernel detects whether raw inputs are f32 or bf16
// (bf16-NaN bit patterns appear when reading f32 data as u16 halves) and all
// raw-input touches + the output write switch on that device-side flag.
// Internal pipeline is canonical bf16 + MFMA.

using bf16 = __hip_bfloat16;
using s16x8 = __attribute__((ext_vector_type(8))) short;
using f32x4 = __attribute__((ext_vector_type(4))) float;

__device__ __forceinline__ float bf2f(bf16 v) { return __bfloat162float(v); }
__device__ __forceinline__ short f2s(float x) {
  bf16 b = __float2bfloat16(x);
  short s;
  __builtin_memcpy(&s, &b, 2);
  return s;
}
// load raw input element i as float, per flag (1 = f32 data, 0 = bf16 data)
__device__ __forceinline__ float ldP(const void* p, size_t i, int f) {
  return f ? ((const float*)p)[i] : bf2f(((const bf16*)p)[i]);
}

// ---------------------------------------------------------------------------
// Probe: scan first 2M u16s of x; bf16-NaN/Inf bit patterns => data is f32.
// ---------------------------------------------------------------------------
__global__ void probe_kernel(const unsigned short* __restrict__ xs, int* __restrict__ flag) {
  __shared__ int cnt[256];
  int tid = threadIdx.x;
  int c = 0;
  for (int i = tid; i < (1 << 21); i += 256) {
    unsigned short u = xs[i];
    if ((u & 0x7F80u) == 0x7F80u) c++;
  }
  cnt[tid] = c;
  __syncthreads();
  for (int s = 128; s > 0; s >>= 1) {
    if (tid < s) cnt[tid] += cnt[tid + s];
    __syncthreads();
  }
  if (tid == 0) flag[0] = (cnt[0] > 0) ? 1 : 0;
}

// ---------------------------------------------------------------------------
// Transpose raw (R x C) -> canonical bf16 (C x R); one matrix per blockIdx.z
// ---------------------------------------------------------------------------
__global__ void transpose_any(const void* __restrict__ in, bf16* __restrict__ out,
                              int R, int C, const int* __restrict__ flagp) {
  const int f = flagp[0];
  __shared__ short tile[32][33];
  size_t base = (size_t)blockIdx.z * R * C;
  short* dst = (short*)out + base;
  int r0 = blockIdx.x * 32, c0 = blockIdx.y * 32;
  int tx = threadIdx.x, ty = threadIdx.y;  // (32, 8)
#pragma unroll
  for (int i = 0; i < 4; ++i)
    tile[ty + i * 8][tx] = f2s(ldP(in, base + (size_t)(r0 + ty + i * 8) * C + c0 + tx, f));
  __syncthreads();
#pragma unroll
  for (int i = 0; i < 4; ++i)
    dst[(size_t)(c0 + ty + i * 8) * R + r0 + tx] = tile[tx][ty + i * 8];
}

// ---------------------------------------------------------------------------
// GEMM: C[M,N](bf16) = A[M,K] @ Bt[N,K]^T + bias[N]
// A may be a raw input (dtype per flag) when a_raw=1, else canonical bf16.
// Bt always canonical bf16. bias raw (element offset boff), dtype per flag.
// 128x128 tile, BK=32, 256 threads, 4 waves, 4x4 16x16x32 MFMA tiles.
// ---------------------------------------------------------------------------
__global__ __launch_bounds__(256) void gemm_bt(
    const void* __restrict__ Ag,
    const bf16* __restrict__ Bt0, const bf16* __restrict__ Bt1,
    const void* __restrict__ bias0, const void* __restrict__ bias1, int boff,
    bf16* __restrict__ out0, bf16* __restrict__ out1,
    int M, int N, int K, const int* __restrict__ flagp, int a_raw) {
  const bf16* Bt = (blockIdx.z == 0) ? Bt0 : Bt1;
  const void* bias = (blockIdx.z == 0) ? bias0 : bias1;
  bf16* Cg = (blockIdx.z == 0) ? out0 : out1;

  const int f = flagp[0];
  const int fa = a_raw ? f : 0;

  __shared__ short lA[128 * 32];
  __shared__ short lB[128 * 32];

  const int tid = threadIdx.x;
  const int lane = tid & 63, w = tid >> 6;
  const int wr = w >> 1, wc = w & 1;
  const int l16 = lane & 15, quad = lane >> 4;
  const int srow = tid >> 2;       // 0..63
  const int scol = (tid & 3) * 8;  // 0,8,16,24

  const size_t rm0 = (size_t)blockIdx.x * 128;
  const size_t cn0 = (size_t)blockIdx.y * 128;

  f32x4 acc[4][4];
#pragma unroll
  for (int i = 0; i < 4; ++i)
#pragma unroll
    for (int j = 0; j < 4; ++j) acc[i][j] = (f32x4){0.f, 0.f, 0.f, 0.f};

  for (int kb = 0; kb < K; kb += 32) {
#pragma unroll
    for (int t = 0; t < 2; ++t) {
      int row = t * 64 + srow;
      size_t aidx = (rm0 + row) * (size_t)K + kb + scol;
      if (fa) {
        const float* ga = (const float*)Ag + aidx;
        float4 p0 = *(const float4*)ga;
        float4 p1 = *(const float4*)(ga + 4);
        s16x8 v;
        v[0] = f2s(p0.x); v[1] = f2s(p0.y); v[2] = f2s(p0.z); v[3] = f2s(p0.w);
        v[4] = f2s(p1.x); v[5] = f2s(p1.y); v[6] = f2s(p1.z); v[7] = f2s(p1.w);
        *(s16x8*)(lA + row * 32 + scol) = v;
      } else {
        *(s16x8*)(lA + row * 32 + scol) =
            *(const s16x8*)((const bf16*)Ag + aidx);
      }
      *(s16x8*)(lB + row * 32 + scol) =
          *(const s16x8*)(Bt + (cn0 + row) * (size_t)K + kb + scol);
    }
    __syncthreads();

    s16x8 af[4], bfv[4];
#pragma unroll
    for (int i = 0; i < 4; ++i) {
      af[i] = *(const s16x8*)(lA + (wr * 64 + i * 16 + l16) * 32 + quad * 8);
      bfv[i] = *(const s16x8*)(lB + (wc * 64 + i * 16 + l16) * 32 + quad * 8);
    }
#pragma unroll
    for (int i = 0; i < 4; ++i)
#pragma unroll
      for (int j = 0; j < 4; ++j)
        acc[i][j] = __builtin_amdgcn_mfma_f32_16x16x32_bf16(af[i], bfv[j], acc[i][j], 0, 0, 0);
    __syncthreads();
  }

  // epilogue: D row = quad*4+reg, col = lane&15 (m89-verified layout)
#pragma unroll
  for (int j = 0; j < 4; ++j) {
    size_t col = cn0 + wc * 64 + j * 16 + l16;
    float bv = bias ? ldP(bias, (size_t)boff + col, f) : 0.f;
#pragma unroll
    for (int i = 0; i < 4; ++i) {
      size_t rowb = rm0 + wr * 64 + i * 16 + quad * 4;
#pragma unroll
      for (int r = 0; r < 4; ++r) {
        float v = acc[i][j][r] + bv;
        Cg[(rowb + r) * (size_t)N + col] = __float2bfloat16(v);
      }
    }
  }
}

// ---------------------------------------------------------------------------
// scores[b, head, c, d] = sum_m q[b,c,m] * kv[b,d,m]  (q,kv canonical bf16)
// ---------------------------------------------------------------------------
__global__ void scores_kernel(const bf16* __restrict__ Q, const bf16* __restrict__ KV,
                              float* __restrict__ S, int head) {
  int b = blockIdx.x, tid = threadIdx.x;  // 64 threads
  __shared__ short lq[6 * 512];
  __shared__ short lk[6 * 512];
  const int4* q4 = (const int4*)(Q + (size_t)b * 6 * 512);
  const int4* k4 = (const int4*)(KV + (size_t)b * 6 * 512);
  int4* lq4 = (int4*)lq;
  int4* lk4 = (int4*)lk;
  for (int i = tid; i < 384; i += 64) { lq4[i] = q4[i]; lk4[i] = k4[i]; }
  __syncthreads();
  if (tid < 36) {
    int c = tid / 6, d = tid % 6;
    const short* qr = lq + c * 512;
    const short* kr = lk + d * 512;
    float s = 0.f;
    for (int i = 0; i < 512; ++i) {
      union { unsigned int u; float f; } a, bb;
      a.u = ((unsigned int)(unsigned short)qr[i]) << 16;
      bb.u = ((unsigned int)(unsigned short)kr[i]) << 16;
      s += a.f * bb.f;
    }
    S[((size_t)b * 5 + head) * 36 + tid] = s;
  }
}

// ---------------------------------------------------------------------------
// Per-batch: softmax(scores) -> cat@linW+linb -> softmax -> A;
// h = A@xg + gb1 -> PReLU -> BN1 -> H(bf16). Also store A (f32).
// ---------------------------------------------------------------------------
__global__ void batch_mid_kernel(const float* __restrict__ S, const bf16* __restrict__ XG,
                                 const void* __restrict__ linW, const void* __restrict__ linb,
                                 const void* __restrict__ gb1, const void* __restrict__ prelu,
                                 const void* __restrict__ g1, const void* __restrict__ b1,
                                 const void* __restrict__ m1, const void* __restrict__ v1,
                                 float* __restrict__ Afull, bf16* __restrict__ H,
                                 const int* __restrict__ flagp) {
  int b = blockIdx.x, tid = threadIdx.x;  // 64 threads
  const int f = flagp[0];
  __shared__ float p[5][6][6];
  __shared__ float Ar[6][6];
  __shared__ float lw[30][6];
  __shared__ float lbv[6];
  __shared__ float sc1[6], sm1[6], sb1[6];

  if (tid < 30) {
    int k = tid / 6, c = tid % 6;
    const float* sp = S + ((size_t)b * 5 + k) * 36 + c * 6;
    float v[6], mx = sp[0];
#pragma unroll
    for (int d = 0; d < 6; ++d) { v[d] = sp[d]; mx = fmaxf(mx, v[d]); }
    float s = 0.f;
#pragma unroll
    for (int d = 0; d < 6; ++d) { v[d] = expf(v[d] - mx); s += v[d]; }
    float inv = 1.f / s;
#pragma unroll
    for (int d = 0; d < 6; ++d) p[k][c][d] = v[d] * inv;
#pragma unroll
    for (int j = 0; j < 6; ++j) lw[tid][j] = ldP(linW, tid * 6 + j, f);
  }
  if (tid < 6) {
    lbv[tid] = ldP(linb, tid, f);
    sc1[tid] = ldP(g1, tid, f) * rsqrtf(ldP(v1, tid, f) + 1e-5f);
    sm1[tid] = ldP(m1, tid, f);
    sb1[tid] = ldP(b1, tid, f);
  }
  __syncthreads();

  if (tid < 6) {
    int c = tid;
    float ap[6];
#pragma unroll
    for (int j = 0; j < 6; ++j) ap[j] = lbv[j];
    for (int k = 0; k < 5; ++k)
#pragma unroll
      for (int d = 0; d < 6; ++d) {
        float pv = p[k][c][d];
#pragma unroll
        for (int j = 0; j < 6; ++j) ap[j] += pv * lw[k * 6 + d][j];
      }
    float mx = ap[0];
#pragma unroll
    for (int j = 1; j < 6; ++j) mx = fmaxf(mx, ap[j]);
    float s = 0.f;
#pragma unroll
    for (int j = 0; j < 6; ++j) { ap[j] = expf(ap[j] - mx); s += ap[j]; }
    float inv = 1.f / s;
#pragma unroll
    for (int j = 0; j < 6; ++j) {
      float a = ap[j] * inv;
      Ar[c][j] = a;
      Afull[(size_t)b * 36 + c * 6 + j] = a;
    }
  }
  __syncthreads();

  float pa = ldP(prelu, 0, f);
  for (int col = tid; col < 512; col += 64) {
    float xg[6];
#pragma unroll
    for (int d = 0; d < 6; ++d) xg[d] = bf2f(XG[((size_t)b * 6 + d) * 512 + col]);
    float gbv = ldP(gb1, col, f);
#pragma unroll
    for (int c = 0; c < 6; ++c) {
      float h = gbv;
#pragma unroll
      for (int d = 0; d < 6; ++d) h += Ar[c][d] * xg[d];
      h = (h >= 0.f) ? h : pa * h;
      h = (h - sm1[c]) * sc1[c] + sb1[c];
      H[((size_t)b * 6 + c) * 512 + col] = __float2bfloat16(h);
    }
  }
}

// ---------------------------------------------------------------------------
// Per-batch: out = BN2(A @ hw + gb2). Output dtype per flag.
// ---------------------------------------------------------------------------
__global__ void batch_out_kernel(const float* __restrict__ Afull, const bf16* __restrict__ HW,
                                 const void* __restrict__ gb2,
                                 const void* __restrict__ g2, const void* __restrict__ b2,
                                 const void* __restrict__ m2, const void* __restrict__ v2,
                                 void* __restrict__ outp, const int* __restrict__ flagp) {
  int b = blockIdx.x, tid = threadIdx.x;  // 64 threads
  const int f = flagp[0];
  __shared__ float Ar[36];
  __shared__ float sc[6], sm[6], sb[6];
  if (tid < 36) Ar[tid] = Afull[(size_t)b * 36 + tid];
  if (tid < 6) {
    sc[tid] = ldP(g2, tid, f) * rsqrtf(ldP(v2, tid, f) + 1e-5f);
    sm[tid] = ldP(m2, tid, f);
    sb[tid] = ldP(b2, tid, f);
  }
  __syncthreads();
  for (int col = tid; col < 256; col += 64) {
    float hw[6];
#pragma unroll
    for (int d = 0; d < 6; ++d) hw[d] = bf2f(HW[((size_t)b * 6 + d) * 256 + col]);
    float gv = ldP(gb2, col, f);
#pragma unroll
    for (int c = 0; c < 6; ++c) {
      float o = gv;
#pragma unroll
      for (int d = 0; d < 6; ++d) o += Ar[c * 6 + d] * hw[d];
      o = (o - sm[c]) * sc[c] + sb[c];
      size_t idx = ((size_t)b * 6 + c) * 256 + col;
      if (f) ((float*)outp)[idx] = o;
      else ((bf16*)outp)[idx] = __float2bfloat16(o);
    }
  }
}

// ---------------------------------------------------------------------------
extern "C" void kernel_launch(void* const* d_in, const int* in_sizes, int n_in,
                              void* d_out, int out_size, void* d_ws, size_t ws_size,
                              hipStream_t stream) {
  const void* x    = d_in[0];
  const void* aW1  = d_in[1];
  const void* ab1  = d_in[2];
  const void* aW2  = d_in[3];
  const void* ab2  = d_in[4];
  const void* linW = d_in[5];
  const void* linb = d_in[6];
  const void* gW1  = d_in[7];
  const void* gb1  = d_in[8];
  const void* gW2  = d_in[9];
  const void* gb2  = d_in[10];
  const void* prelu = d_in[11];
  const void* bn1g = d_in[12];
  const void* bn1b = d_in[13];
  const void* bn1m = d_in[14];
  const void* bn1v = d_in[15];
  const void* bn2g = d_in[16];
  const void* bn2b = d_in[17];
  const void* bn2m = d_in[18];
  const void* bn2v = d_in[19];

  char* ws = (char*)d_ws;
  // layout (bytes), total = 65,667,328 (~62.6 MB):
  int*  flag = (int*)(ws + 0);           // 256 B region
  bf16* W1T  = (bf16*)(ws + 256);        // 5 x 512 x 1024   (5.24 MB)
  bf16* W2T  = (bf16*)(ws + 5243136);    // 5 x 512 x 1024   (5.24 MB)
  bf16* G1T  = (bf16*)(ws + 10486016);   // 512 x 1024       (1.05 MB)
  bf16* G2T  = (bf16*)(ws + 11534592);   // 256 x 512        (0.26 MB)
  float* S   = (float*)(ws + 11796736);  // 4096 x 5 x 36    (2.95 MB)
  float* Af  = (float*)(ws + 14745856);  // 4096 x 36        (0.59 MB)
  bf16* BufA = (bf16*)(ws + 15335680);   // 24576 x 512: Q, then XG, then HW
  bf16* BufB = (bf16*)(ws + 40501504);   // 24576 x 512: KV, then H

  probe_kernel<<<1, 256, 0, stream>>>((const unsigned short*)x, flag);

  dim3 tb(32, 8);
  transpose_any<<<dim3(32, 16, 5), tb, 0, stream>>>(aW1, W1T, 1024, 512, flag);
  transpose_any<<<dim3(32, 16, 5), tb, 0, stream>>>(aW2, W2T, 1024, 512, flag);
  transpose_any<<<dim3(32, 16, 1), tb, 0, stream>>>(gW1, G1T, 1024, 512, flag);
  transpose_any<<<dim3(16, 8, 1),  tb, 0, stream>>>(gW2, G2T, 512, 256, flag);

  // per head: Q,KV GEMM (z=2, A = raw x) then scores
  for (int k = 0; k < 5; ++k) {
    gemm_bt<<<dim3(192, 4, 2), 256, 0, stream>>>(
        x, W1T + (size_t)k * 512 * 1024, W2T + (size_t)k * 512 * 1024,
        ab1, ab2, k * 512, BufA, BufB, 24576, 512, 1024, flag, 1);
    scores_kernel<<<4096, 64, 0, stream>>>(BufA, BufB, S, k);
  }

  // XG = X @ gW1 (Q dead -> BufA); A = raw x
  gemm_bt<<<dim3(192, 4, 1), 256, 0, stream>>>(
      x, G1T, G1T, nullptr, nullptr, 0, BufA, BufA, 24576, 512, 1024, flag, 1);

  // softmaxes + A + H (KV dead -> H into BufB)
  batch_mid_kernel<<<4096, 64, 0, stream>>>(S, BufA, linW, linb, gb1, prelu,
                                            bn1g, bn1b, bn1m, bn1v, Af, BufB, flag);

  // HW = H @ gW2 (XG dead -> HW into BufA); A = canonical bf16
  gemm_bt<<<dim3(192, 2, 1), 256, 0, stream>>>(
      BufB, G2T, G2T, nullptr, nullptr, 0, BufA, BufA, 24576, 256, 512, flag, 0);

  batch_out_kernel<<<4096, 64, 0, stream>>>(Af, BufA, gb2, bn2g, bn2b, bn2m, bn2v,
                                            d_out, flag);
}

// Round 4
// 816.252 us; speedup vs baseline: 3.5414x; 3.5414x over previous
//
#include <hip/hip_runtime.h>
#include <hip/hip_bf16.h>

// MHAGCN: x(4096,6,1024) f32 -> out(4096,6,256) f32. (Dtype proven in R3:
// bf16 reads NaN'd, f32 flag-path passed.) Internal pipeline bf16 + MFMA.
// R4: probe deleted; x pre-converted to bf16 (if ws allows); GLL staging
// reintroduced; scores inner loop vectorized.

using bf16 = __hip_bfloat16;
using s16x8 = __attribute__((ext_vector_type(8))) short;
using f32x4 = __attribute__((ext_vector_type(4))) float;

#define AS1(p) ((__attribute__((address_space(1))) void*)((void*)(p)))
#define AS3(p) ((__attribute__((address_space(3))) void*)(p))

#if defined(__has_builtin)
#if __has_builtin(__builtin_amdgcn_global_load_lds)
#define HAVE_GLL 1
#endif
#endif

__device__ __forceinline__ float s2f(short s) {
  union { unsigned int u; float f; } c;
  c.u = ((unsigned int)(unsigned short)s) << 16;
  return c.f;
}
__device__ __forceinline__ short f2s(float x) {
  bf16 b = __float2bfloat16(x);
  short s;
  __builtin_memcpy(&s, &b, 2);
  return s;
}

// ---------------------------------------------------------------------------
// x (f32) -> bf16, 8 els/thread
// ---------------------------------------------------------------------------
__global__ void cvt_f32_bf16(const float* __restrict__ in, bf16* __restrict__ out, int n8) {
  int i = blockIdx.x * blockDim.x + threadIdx.x;
  if (i >= n8) return;
  float4 p0 = ((const float4*)in)[i * 2];
  float4 p1 = ((const float4*)in)[i * 2 + 1];
  s16x8 v;
  v[0] = f2s(p0.x); v[1] = f2s(p0.y); v[2] = f2s(p0.z); v[3] = f2s(p0.w);
  v[4] = f2s(p1.x); v[5] = f2s(p1.y); v[6] = f2s(p1.z); v[7] = f2s(p1.w);
  ((s16x8*)out)[i] = v;
}

// ---------------------------------------------------------------------------
// Transpose f32 (R x C) -> bf16 (C x R); one matrix per blockIdx.z
// ---------------------------------------------------------------------------
__global__ void transpose_f2b(const float* __restrict__ in, bf16* __restrict__ out,
                              int R, int C) {
  __shared__ short tile[32][33];
  const float* src = in + (size_t)blockIdx.z * R * C;
  short* dst = (short*)out + (size_t)blockIdx.z * R * C;
  int r0 = blockIdx.x * 32, c0 = blockIdx.y * 32;
  int tx = threadIdx.x, ty = threadIdx.y;  // (32, 8)
#pragma unroll
  for (int i = 0; i < 4; ++i)
    tile[ty + i * 8][tx] = f2s(src[(size_t)(r0 + ty + i * 8) * C + c0 + tx]);
  __syncthreads();
#pragma unroll
  for (int i = 0; i < 4; ++i)
    dst[(size_t)(c0 + ty + i * 8) * R + r0 + tx] = tile[tx][ty + i * 8];
}

// ---------------------------------------------------------------------------
// GEMM: C[M,N](bf16) = A[M,K] @ Bt[N,K]^T + bias[N](f32)
// AF32: A is raw f32 (cvt during staging); else bf16 (GLL staging).
// 128x128 tile, BK=32, 256 threads, 4 waves (2x2), 4x4 16x16x32 MFMA tiles.
// grid.z selects (Bt,bias,out). Requires M%128==0, N%128==0, K%32==0.
// ---------------------------------------------------------------------------
template <int AF32>
__global__ __launch_bounds__(256) void gemm_bt(
    const void* __restrict__ Ag,
    const bf16* __restrict__ Bt0, const bf16* __restrict__ Bt1,
    const float* __restrict__ bias0, const float* __restrict__ bias1, int boff,
    bf16* __restrict__ out0, bf16* __restrict__ out1,
    int M, int N, int K) {
  const bf16* Bt = (blockIdx.z == 0) ? Bt0 : Bt1;
  const float* bias = (blockIdx.z == 0) ? bias0 : bias1;
  bf16* Cg = (blockIdx.z == 0) ? out0 : out1;

  __shared__ short lA[128 * 32];
  __shared__ short lB[128 * 32];

  const int tid = threadIdx.x;
  const int lane = tid & 63, w = tid >> 6;
  const int wr = w >> 1, wc = w & 1;
  const int l16 = lane & 15, quad = lane >> 4;
  const int lrow = lane >> 2, lcol = (lane & 3) * 8;  // staging lane map

  const size_t rm0 = (size_t)blockIdx.x * 128;
  const size_t cn0 = (size_t)blockIdx.y * 128;

  f32x4 acc[4][4];
#pragma unroll
  for (int i = 0; i < 4; ++i)
#pragma unroll
    for (int j = 0; j < 4; ++j) acc[i][j] = (f32x4){0.f, 0.f, 0.f, 0.f};

  for (int kb = 0; kb < K; kb += 32) {
    // 8 chunks of 16 rows x 32 cols per matrix; wave w covers chunks 2w,2w+1.
    // Chunk LDS base is wave-uniform; lane deposits 16B at base + lane*16.
#pragma unroll
    for (int t = 0; t < 2; ++t) {
      int chunk = w * 2 + t;
      int row = chunk * 16 + lrow;
      const bf16* gb = Bt + (cn0 + row) * (size_t)K + kb + lcol;
#ifdef HAVE_GLL
      __builtin_amdgcn_global_load_lds(AS1(gb), AS3(lB + chunk * 512), 16, 0, 0);
#else
      *(s16x8*)(lB + chunk * 512 + lane * 8) = *(const s16x8*)gb;
#endif
      if (AF32) {
        const float* ga = (const float*)Ag + (rm0 + row) * (size_t)K + kb + lcol;
        float4 p0 = *(const float4*)ga;
        float4 p1 = *(const float4*)(ga + 4);
        s16x8 v;
        v[0] = f2s(p0.x); v[1] = f2s(p0.y); v[2] = f2s(p0.z); v[3] = f2s(p0.w);
        v[4] = f2s(p1.x); v[5] = f2s(p1.y); v[6] = f2s(p1.z); v[7] = f2s(p1.w);
        *(s16x8*)(lA + chunk * 512 + lane * 8) = v;
      } else {
        const bf16* ga = (const bf16*)Ag + (rm0 + row) * (size_t)K + kb + lcol;
#ifdef HAVE_GLL
        __builtin_amdgcn_global_load_lds(AS1(ga), AS3(lA + chunk * 512), 16, 0, 0);
#else
        *(s16x8*)(lA + chunk * 512 + lane * 8) = *(const s16x8*)ga;
#endif
      }
    }
    __syncthreads();

    s16x8 af[4], bfv[4];
#pragma unroll
    for (int i = 0; i < 4; ++i) {
      af[i] = *(const s16x8*)(lA + (wr * 64 + i * 16 + l16) * 32 + quad * 8);
      bfv[i] = *(const s16x8*)(lB + (wc * 64 + i * 16 + l16) * 32 + quad * 8);
    }
#pragma unroll
    for (int i = 0; i < 4; ++i)
#pragma unroll
      for (int j = 0; j < 4; ++j)
        acc[i][j] = __builtin_amdgcn_mfma_f32_16x16x32_bf16(af[i], bfv[j], acc[i][j], 0, 0, 0);
    __syncthreads();
  }

  // epilogue: D row = quad*4+reg, col = lane&15 (m89-verified layout)
#pragma unroll
  for (int j = 0; j < 4; ++j) {
    size_t col = cn0 + wc * 64 + j * 16 + l16;
    float bv = bias ? bias[boff + col] : 0.f;
#pragma unroll
    for (int i = 0; i < 4; ++i) {
      size_t rowb = rm0 + wr * 64 + i * 16 + quad * 4;
#pragma unroll
      for (int r = 0; r < 4; ++r) {
        float v = acc[i][j][r] + bv;
        Cg[(rowb + r) * (size_t)N + col] = __float2bfloat16(v);
      }
    }
  }
}

// ---------------------------------------------------------------------------
// scores[b, head, c, d] = sum_m q[b,c,m] * kv[b,d,m]  (q,kv bf16, 6x512/batch)
// ---------------------------------------------------------------------------
__global__ void scores_kernel(const bf16* __restrict__ Q, const bf16* __restrict__ KV,
                              float* __restrict__ S, int head) {
  int b = blockIdx.x, tid = threadIdx.x;  // 64 threads
  __shared__ short lq[6 * 512];
  __shared__ short lk[6 * 512];
  const int4* q4 = (const int4*)(Q + (size_t)b * 6 * 512);
  const int4* k4 = (const int4*)(KV + (size_t)b * 6 * 512);
  int4* lq4 = (int4*)lq;
  int4* lk4 = (int4*)lk;
  for (int i = tid; i < 384; i += 64) { lq4[i] = q4[i]; lk4[i] = k4[i]; }
  __syncthreads();
  if (tid < 36) {
    int c = tid / 6, d = tid % 6;
    const s16x8* qr = (const s16x8*)(lq + c * 512);
    const s16x8* kr = (const s16x8*)(lk + d * 512);
    float s = 0.f;
    for (int i = 0; i < 64; ++i) {
      s16x8 a = qr[i], bb = kr[i];
#pragma unroll
      for (int j = 0; j < 8; ++j) s += s2f(a[j]) * s2f(bb[j]);
    }
    S[((size_t)b * 5 + head) * 36 + tid] = s;
  }
}

// ---------------------------------------------------------------------------
// Per-batch: softmax(scores) -> cat@linW+linb -> softmax -> A;
// h = A@xg + gb1 -> PReLU -> BN1 -> H(bf16). Also store A (f32).
// ---------------------------------------------------------------------------
__global__ void batch_mid_kernel(const float* __restrict__ S, const bf16* __restrict__ XG,
                                 const float* __restrict__ linW, const float* __restrict__ linb,
                                 const float* __restrict__ gb1, const float* __restrict__ prelu,
                                 const float* __restrict__ g1, const float* __restrict__ b1,
                                 const float* __restrict__ m1, const float* __restrict__ v1,
                                 float* __restrict__ Afull, bf16* __restrict__ H) {
  int b = blockIdx.x, tid = threadIdx.x;  // 64 threads
  __shared__ float p[5][6][6];
  __shared__ float Ar[6][6];
  __shared__ float lw[30][6];
  __shared__ float lbv[6];
  __shared__ float sc1[6], sm1[6], sb1[6];

  if (tid < 30) {
    int k = tid / 6, c = tid % 6;
    const float* sp = S + ((size_t)b * 5 + k) * 36 + c * 6;
    float v[6], mx = sp[0];
#pragma unroll
    for (int d = 0; d < 6; ++d) { v[d] = sp[d]; mx = fmaxf(mx, v[d]); }
    float s = 0.f;
#pragma unroll
    for (int d = 0; d < 6; ++d) { v[d] = expf(v[d] - mx); s += v[d]; }
    float inv = 1.f / s;
#pragma unroll
    for (int d = 0; d < 6; ++d) p[k][c][d] = v[d] * inv;
#pragma unroll
    for (int j = 0; j < 6; ++j) lw[tid][j] = linW[tid * 6 + j];
  }
  if (tid < 6) {
    lbv[tid] = linb[tid];
    sc1[tid] = g1[tid] * rsqrtf(v1[tid] + 1e-5f);
    sm1[tid] = m1[tid];
    sb1[tid] = b1[tid];
  }
  __syncthreads();

  if (tid < 6) {
    int c = tid;
    float ap[6];
#pragma unroll
    for (int j = 0; j < 6; ++j) ap[j] = lbv[j];
    for (int k = 0; k < 5; ++k)
#pragma unroll
      for (int d = 0; d < 6; ++d) {
        float pv = p[k][c][d];
#pragma unroll
        for (int j = 0; j < 6; ++j) ap[j] += pv * lw[k * 6 + d][j];
      }
    float mx = ap[0];
#pragma unroll
    for (int j = 1; j < 6; ++j) mx = fmaxf(mx, ap[j]);
    float s = 0.f;
#pragma unroll
    for (int j = 0; j < 6; ++j) { ap[j] = expf(ap[j] - mx); s += ap[j]; }
    float inv = 1.f / s;
#pragma unroll
    for (int j = 0; j < 6; ++j) {
      float a = ap[j] * inv;
      Ar[c][j] = a;
      Afull[(size_t)b * 36 + c * 6 + j] = a;
    }
  }
  __syncthreads();

  float pa = prelu[0];
  for (int col = tid; col < 512; col += 64) {
    float xg[6];
#pragma unroll
    for (int d = 0; d < 6; ++d) xg[d] = s2f(((const short*)XG)[((size_t)b * 6 + d) * 512 + col]);
    float gbv = gb1[col];
#pragma unroll
    for (int c = 0; c < 6; ++c) {
      float h = gbv;
#pragma unroll
      for (int d = 0; d < 6; ++d) h += Ar[c][d] * xg[d];
      h = (h >= 0.f) ? h : pa * h;
      h = (h - sm1[c]) * sc1[c] + sb1[c];
      H[((size_t)b * 6 + c) * 512 + col] = __float2bfloat16(h);
    }
  }
}

// ---------------------------------------------------------------------------
// Per-batch: out(f32) = BN2(A @ hw + gb2)
// ---------------------------------------------------------------------------
__global__ void batch_out_kernel(const float* __restrict__ Afull, const bf16* __restrict__ HW,
                                 const float* __restrict__ gb2,
                                 const float* __restrict__ g2, const float* __restrict__ b2,
                                 const float* __restrict__ m2, const float* __restrict__ v2,
                                 float* __restrict__ out) {
  int b = blockIdx.x, tid = threadIdx.x;  // 64 threads
  __shared__ float Ar[36];
  __shared__ float sc[6], sm[6], sb[6];
  if (tid < 36) Ar[tid] = Afull[(size_t)b * 36 + tid];
  if (tid < 6) {
    sc[tid] = g2[tid] * rsqrtf(v2[tid] + 1e-5f);
    sm[tid] = m2[tid];
    sb[tid] = b2[tid];
  }
  __syncthreads();
  for (int col = tid; col < 256; col += 64) {
    float hw[6];
#pragma unroll
    for (int d = 0; d < 6; ++d) hw[d] = s2f(((const short*)HW)[((size_t)b * 6 + d) * 256 + col]);
    float gv = gb2[col];
#pragma unroll
    for (int c = 0; c < 6; ++c) {
      float o = gv;
#pragma unroll
      for (int d = 0; d < 6; ++d) o += Ar[c * 6 + d] * hw[d];
      o = (o - sm[c]) * sc[c] + sb[c];
      out[((size_t)b * 6 + c) * 256 + col] = o;
    }
  }
}

// ---------------------------------------------------------------------------
extern "C" void kernel_launch(void* const* d_in, const int* in_sizes, int n_in,
                              void* d_out, int out_size, void* d_ws, size_t ws_size,
                              hipStream_t stream) {
  const float* x    = (const float*)d_in[0];
  const float* aW1  = (const float*)d_in[1];
  const float* ab1  = (const float*)d_in[2];
  const float* aW2  = (const float*)d_in[3];
  const float* ab2  = (const float*)d_in[4];
  const float* linW = (const float*)d_in[5];
  const float* linb = (const float*)d_in[6];
  const float* gW1  = (const float*)d_in[7];
  const float* gb1  = (const float*)d_in[8];
  const float* gW2  = (const float*)d_in[9];
  const float* gb2  = (const float*)d_in[10];
  const float* prelu = (const float*)d_in[11];
  const float* bn1g = (const float*)d_in[12];
  const float* bn1b = (const float*)d_in[13];
  const float* bn1m = (const float*)d_in[14];
  const float* bn1v = (const float*)d_in[15];
  const float* bn2g = (const float*)d_in[16];
  const float* bn2b = (const float*)d_in[17];
  const float* bn2m = (const float*)d_in[18];
  const float* bn2v = (const float*)d_in[19];

  char* ws = (char*)d_ws;
  // layout (bytes): base 65.7 MB; +50.3 MB Xb if ws allows
  bf16* W1T  = (bf16*)(ws + 0);          // 5 x 512 x 1024
  bf16* W2T  = (bf16*)(ws + 5242880);    // 5 x 512 x 1024
  bf16* G1T  = (bf16*)(ws + 10485760);   // 512 x 1024
  bf16* G2T  = (bf16*)(ws + 11534336);   // 256 x 512
  float* S   = (float*)(ws + 11796480);  // 4096 x 5 x 36
  float* Af  = (float*)(ws + 14745600);  // 4096 x 36
  bf16* BufA = (bf16*)(ws + 15335424);   // 24576 x 512: Q, then XG, then HW
  bf16* BufB = (bf16*)(ws + 40501248);   // 24576 x 512: KV, then H
  bf16* Xb   = (bf16*)(ws + 65667072);   // 24576 x 1024 (optional)
  const bool big = ws_size >= 115998720ull;

  dim3 tb(32, 8);
  transpose_f2b<<<dim3(32, 16, 5), tb, 0, stream>>>(aW1, W1T, 1024, 512);
  transpose_f2b<<<dim3(32, 16, 5), tb, 0, stream>>>(aW2, W2T, 1024, 512);
  transpose_f2b<<<dim3(32, 16, 1), tb, 0, stream>>>(gW1, G1T, 1024, 512);
  transpose_f2b<<<dim3(16, 8, 1),  tb, 0, stream>>>(gW2, G2T, 512, 256);
  if (big) cvt_f32_bf16<<<12288, 256, 0, stream>>>(x, Xb, 3145728);

  // per head: Q,KV GEMM (z=2) then scores
  for (int k = 0; k < 5; ++k) {
    const bf16* w1 = W1T + (size_t)k * 512 * 1024;
    const bf16* w2 = W2T + (size_t)k * 512 * 1024;
    if (big)
      gemm_bt<0><<<dim3(192, 4, 2), 256, 0, stream>>>(
          Xb, w1, w2, ab1, ab2, k * 512, BufA, BufB, 24576, 512, 1024);
    else
      gemm_bt<1><<<dim3(192, 4, 2), 256, 0, stream>>>(
          x, w1, w2, ab1, ab2, k * 512, BufA, BufB, 24576, 512, 1024);
    scores_kernel<<<4096, 64, 0, stream>>>(BufA, BufB, S, k);
  }

  // XG = X @ gW1 (Q dead -> BufA)
  if (big)
    gemm_bt<0><<<dim3(192, 4, 1), 256, 0, stream>>>(
        Xb, G1T, G1T, nullptr, nullptr, 0, BufA, BufA, 24576, 512, 1024);
  else
    gemm_bt<1><<<dim3(192, 4, 1), 256, 0, stream>>>(
        x, G1T, G1T, nullptr, nullptr, 0, BufA, BufA, 24576, 512, 1024);

  // softmaxes + A + H (KV dead -> H into BufB)
  batch_mid_kernel<<<4096, 64, 0, stream>>>(S, BufA, linW, linb, gb1, prelu,
                                            bn1g, bn1b, bn1m, bn1v, Af, BufB);

  // HW = H @ gW2 (XG dead -> HW into BufA)
  gemm_bt<0><<<dim3(192, 2, 1), 256, 0, stream>>>(
      BufB, G2T, G2T, nullptr, nullptr, 0, BufA, BufA, 24576, 256, 512);

  batch_out_kernel<<<4096, 64, 0, stream>>>(Af, BufA, gb2, bn2g, bn2b, bn2m, bn2v,
                                            (float*)d_out);
}

// Round 6
// 719.284 us; speedup vs baseline: 4.0188x; 1.1348x over previous
//
#include <hip/hip_runtime.h>
#include <hip/hip_bf16.h>

// MHAGCN: x(4096,6,1024) f32 -> out(4096,6,256) f32. Internal bf16 + MFMA.
// R6: fix scores_mfma block-diagonal write (R5 wrote b1 scores against b0's
// KV columns: n=l16 indexes the same {b0:0-7, b1:8-15} packing as m).
// XOR-swizzled LDS kept from R5 to A/B its conflict effect vs R4 counters.

using bf16 = __hip_bfloat16;
using s16x8 = __attribute__((ext_vector_type(8))) short;
using f32x4 = __attribute__((ext_vector_type(4))) float;

#define AS1(p) ((__attribute__((address_space(1))) void*)((void*)(p)))
#define AS3(p) ((__attribute__((address_space(3))) void*)(p))

#if defined(__has_builtin)
#if __has_builtin(__builtin_amdgcn_global_load_lds)
#define HAVE_GLL 1
#endif
#endif

__device__ __forceinline__ float s2f(short s) {
  union { unsigned int u; float f; } c;
  c.u = ((unsigned int)(unsigned short)s) << 16;
  return c.f;
}
__device__ __forceinline__ short f2s(float x) {
  bf16 b = __float2bfloat16(x);
  short s;
  __builtin_memcpy(&s, &b, 2);
  return s;
}

// ---------------------------------------------------------------------------
// x (f32) -> bf16, 8 els/thread
// ---------------------------------------------------------------------------
__global__ void cvt_f32_bf16(const float* __restrict__ in, bf16* __restrict__ out, int n8) {
  int i = blockIdx.x * blockDim.x + threadIdx.x;
  if (i >= n8) return;
  float4 p0 = ((const float4*)in)[i * 2];
  float4 p1 = ((const float4*)in)[i * 2 + 1];
  s16x8 v;
  v[0] = f2s(p0.x); v[1] = f2s(p0.y); v[2] = f2s(p0.z); v[3] = f2s(p0.w);
  v[4] = f2s(p1.x); v[5] = f2s(p1.y); v[6] = f2s(p1.z); v[7] = f2s(p1.w);
  ((s16x8*)out)[i] = v;
}

// ---------------------------------------------------------------------------
// Transpose f32 (R x C) -> bf16 (C x R); one matrix per blockIdx.z
// ---------------------------------------------------------------------------
__global__ void transpose_f2b(const float* __restrict__ in, bf16* __restrict__ out,
                              int R, int C) {
  __shared__ short tile[32][33];
  const float* src = in + (size_t)blockIdx.z * R * C;
  short* dst = (short*)out + (size_t)blockIdx.z * R * C;
  int r0 = blockIdx.x * 32, c0 = blockIdx.y * 32;
  int tx = threadIdx.x, ty = threadIdx.y;  // (32, 8)
#pragma unroll
  for (int i = 0; i < 4; ++i)
    tile[ty + i * 8][tx] = f2s(src[(size_t)(r0 + ty + i * 8) * C + c0 + tx]);
  __syncthreads();
#pragma unroll
  for (int i = 0; i < 4; ++i)
    dst[(size_t)(c0 + ty + i * 8) * R + r0 + tx] = tile[tx][ty + i * 8];
}

// ---------------------------------------------------------------------------
// GEMM: C[M,N](bf16) = A[M,K] @ Bt[N,K]^T + bias[N](f32)
// 128x128 tile, BK=32, 256 threads, 4 waves (2x2), 4x4 16x16x32 MFMA tiles.
// LDS XOR swizzle: 16B unit (row,q) lives at slot q^((row>>1)&3); reader
// inverts. GLL-compatible (dest stays chunk+lane*16; only the global source
// column is permuted inside the 64B row segment).
// grid.z selects (Bt,bias,out). Requires M%128==0, N%128==0, K%32==0.
// ---------------------------------------------------------------------------
template <int AF32>
__global__ __launch_bounds__(256) void gemm_bt(
    const void* __restrict__ Ag,
    const bf16* __restrict__ Bt0, const bf16* __restrict__ Bt1,
    const float* __restrict__ bias0, const float* __restrict__ bias1, int boff,
    bf16* __restrict__ out0, bf16* __restrict__ out1,
    int M, int N, int K) {
  const bf16* Bt = (blockIdx.z == 0) ? Bt0 : Bt1;
  const float* bias = (blockIdx.z == 0) ? bias0 : bias1;
  bf16* Cg = (blockIdx.z == 0) ? out0 : out1;

  __shared__ short lA[128 * 32];
  __shared__ short lB[128 * 32];

  const int tid = threadIdx.x;
  const int lane = tid & 63, w = tid >> 6;
  const int wr = w >> 1, wc = w & 1;
  const int l16 = lane & 15, quad = lane >> 4;
  const int lrow = lane >> 2;                              // 0..15 within chunk
  const int scol = (((lane & 3) ^ ((lane >> 3) & 3)) * 8); // swizzled col (shorts)

  const size_t rm0 = (size_t)blockIdx.x * 128;
  const size_t cn0 = (size_t)blockIdx.y * 128;

  f32x4 acc[4][4];
#pragma unroll
  for (int i = 0; i < 4; ++i)
#pragma unroll
    for (int j = 0; j < 4; ++j) acc[i][j] = (f32x4){0.f, 0.f, 0.f, 0.f};

  for (int kb = 0; kb < K; kb += 32) {
    // 8 chunks of 16 rows x 32 cols per matrix; wave w covers chunks 2w,2w+1.
#pragma unroll
    for (int t = 0; t < 2; ++t) {
      int chunk = w * 2 + t;
      int row = chunk * 16 + lrow;
      const bf16* gb = Bt + (cn0 + row) * (size_t)K + kb + scol;
#ifdef HAVE_GLL
      __builtin_amdgcn_global_load_lds(AS1(gb), AS3(lB + chunk * 512), 16, 0, 0);
#else
      *(s16x8*)(lB + chunk * 512 + lane * 8) = *(const s16x8*)gb;
#endif
      if (AF32) {
        const float* ga = (const float*)Ag + (rm0 + row) * (size_t)K + kb + scol;
        float4 p0 = *(const float4*)ga;
        float4 p1 = *(const float4*)(ga + 4);
        s16x8 v;
        v[0] = f2s(p0.x); v[1] = f2s(p0.y); v[2] = f2s(p0.z); v[3] = f2s(p0.w);
        v[4] = f2s(p1.x); v[5] = f2s(p1.y); v[6] = f2s(p1.z); v[7] = f2s(p1.w);
        *(s16x8*)(lA + chunk * 512 + lane * 8) = v;
      } else {
        const bf16* ga = (const bf16*)Ag + (rm0 + row) * (size_t)K + kb + scol;
#ifdef HAVE_GLL
        __builtin_amdgcn_global_load_lds(AS1(ga), AS3(lA + chunk * 512), 16, 0, 0);
#else
        *(s16x8*)(lA + chunk * 512 + lane * 8) = *(const s16x8*)ga;
#endif
      }
    }
    __syncthreads();

    const int q2 = (quad ^ ((l16 >> 1) & 3)) * 8;  // swizzled read col (shorts)
    s16x8 af[4], bfv[4];
#pragma unroll
    for (int i = 0; i < 4; ++i) {
      af[i] = *(const s16x8*)(lA + (wr * 64 + i * 16 + l16) * 32 + q2);
      bfv[i] = *(const s16x8*)(lB + (wc * 64 + i * 16 + l16) * 32 + q2);
    }
#pragma unroll
    for (int i = 0; i < 4; ++i)
#pragma unroll
      for (int j = 0; j < 4; ++j)
        acc[i][j] = __builtin_amdgcn_mfma_f32_16x16x32_bf16(af[i], bfv[j], acc[i][j], 0, 0, 0);
    __syncthreads();
  }

  // epilogue: D row = quad*4+reg, col = lane&15 (m89-verified layout)
#pragma unroll
  for (int j = 0; j < 4; ++j) {
    size_t col = cn0 + wc * 64 + j * 16 + l16;
    float bv = bias ? bias[boff + col] : 0.f;
#pragma unroll
    for (int i = 0; i < 4; ++i) {
      size_t rowb = rm0 + wr * 64 + i * 16 + quad * 4;
#pragma unroll
      for (int r = 0; r < 4; ++r) {
        float v = acc[i][j][r] + bv;
        Cg[(rowb + r) * (size_t)N + col] = __float2bfloat16(v);
      }
    }
  }
}

// ---------------------------------------------------------------------------
// MFMA scores: per wave, 2 batches packed as rows {b0: 0-7, b1: 8-15} on BOTH
// m and n. D[m=quad*4+r][n=l16]. Valid outputs are the diagonal blocks:
// (m<6, n<6) -> b0;  (8<=m<14, 8<=n<14) -> b1. Off-diagonal blocks are
// cross-batch garbage and must not be written (R5 bug).
// ---------------------------------------------------------------------------
__global__ __launch_bounds__(256) void scores_mfma(
    const bf16* __restrict__ Q, const bf16* __restrict__ KV,
    float* __restrict__ S, int head) {
  const int tid = threadIdx.x;
  const int lane = tid & 63, w = tid >> 6;
  const int l16 = lane & 15, quad = lane >> 4;
  const int b0 = (blockIdx.x * 4 + w) * 2;  // batches b0, b0+1

  int gr = (l16 < 8) ? (b0 * 6 + l16) : ((b0 + 1) * 6 + (l16 - 8));
  if (gr > 24575) gr = 24575;  // clamp padding rows (l16=6,7,14,15 unused)

  const short* qrow = (const short*)Q + (size_t)gr * 512 + quad * 8;
  const short* krow = (const short*)KV + (size_t)gr * 512 + quad * 8;

  f32x4 acc = (f32x4){0.f, 0.f, 0.f, 0.f};
#pragma unroll
  for (int kk = 0; kk < 16; ++kk) {
    s16x8 a = *(const s16x8*)(qrow + kk * 32);
    s16x8 b = *(const s16x8*)(krow + kk * 32);
    acc = __builtin_amdgcn_mfma_f32_16x16x32_bf16(a, b, acc, 0, 0, 0);
  }

  if (l16 < 6) {  // n -> b0 KV rows
#pragma unroll
    for (int r = 0; r < 4; ++r) {
      int m = quad * 4 + r;
      if (m < 6)
        S[((size_t)b0 * 5 + head) * 36 + m * 6 + l16] = acc[r];
    }
  } else if (l16 >= 8 && l16 < 14) {  // n -> b1 KV rows
#pragma unroll
    for (int r = 0; r < 4; ++r) {
      int m = quad * 4 + r;
      if (m >= 8 && m < 14)
        S[((size_t)(b0 + 1) * 5 + head) * 36 + (m - 8) * 6 + (l16 - 8)] = acc[r];
    }
  }
}

// ---------------------------------------------------------------------------
// Per-batch: softmax(scores) -> cat@linW+linb -> softmax -> A;
// h = A@xg + gb1 -> PReLU -> BN1 -> H(bf16). Also store A (f32).
// ---------------------------------------------------------------------------
__global__ void batch_mid_kernel(const float* __restrict__ S, const bf16* __restrict__ XG,
                                 const float* __restrict__ linW, const float* __restrict__ linb,
                                 const float* __restrict__ gb1, const float* __restrict__ prelu,
                                 const float* __restrict__ g1, const float* __restrict__ b1,
                                 const float* __restrict__ m1, const float* __restrict__ v1,
                                 float* __restrict__ Afull, bf16* __restrict__ H) {
  int b = blockIdx.x, tid = threadIdx.x;  // 64 threads
  __shared__ float p[5][6][6];
  __shared__ float Ar[6][6];
  __shared__ float lw[30][6];
  __shared__ float lbv[6];
  __shared__ float sc1[6], sm1[6], sb1[6];

  if (tid < 30) {
    int k = tid / 6, c = tid % 6;
    const float* sp = S + ((size_t)b * 5 + k) * 36 + c * 6;
    float v[6], mx = sp[0];
#pragma unroll
    for (int d = 0; d < 6; ++d) { v[d] = sp[d]; mx = fmaxf(mx, v[d]); }
    float s = 0.f;
#pragma unroll
    for (int d = 0; d < 6; ++d) { v[d] = expf(v[d] - mx); s += v[d]; }
    float inv = 1.f / s;
#pragma unroll
    for (int d = 0; d < 6; ++d) p[k][c][d] = v[d] * inv;
#pragma unroll
    for (int j = 0; j < 6; ++j) lw[tid][j] = linW[tid * 6 + j];
  }
  if (tid < 6) {
    lbv[tid] = linb[tid];
    sc1[tid] = g1[tid] * rsqrtf(v1[tid] + 1e-5f);
    sm1[tid] = m1[tid];
    sb1[tid] = b1[tid];
  }
  __syncthreads();

  if (tid < 6) {
    int c = tid;
    float ap[6];
#pragma unroll
    for (int j = 0; j < 6; ++j) ap[j] = lbv[j];
    for (int k = 0; k < 5; ++k)
#pragma unroll
      for (int d = 0; d < 6; ++d) {
        float pv = p[k][c][d];
#pragma unroll
        for (int j = 0; j < 6; ++j) ap[j] += pv * lw[k * 6 + d][j];
      }
    float mx = ap[0];
#pragma unroll
    for (int j = 1; j < 6; ++j) mx = fmaxf(mx, ap[j]);
    float s = 0.f;
#pragma unroll
    for (int j = 0; j < 6; ++j) { ap[j] = expf(ap[j] - mx); s += ap[j]; }
    float inv = 1.f / s;
#pragma unroll
    for (int j = 0; j < 6; ++j) {
      float a = ap[j] * inv;
      Ar[c][j] = a;
      Afull[(size_t)b * 36 + c * 6 + j] = a;
    }
  }
  __syncthreads();

  float pa = prelu[0];
  for (int col = tid; col < 512; col += 64) {
    float xg[6];
#pragma unroll
    for (int d = 0; d < 6; ++d) xg[d] = s2f(((const short*)XG)[((size_t)b * 6 + d) * 512 + col]);
    float gbv = gb1[col];
#pragma unroll
    for (int c = 0; c < 6; ++c) {
      float h = gbv;
#pragma unroll
      for (int d = 0; d < 6; ++d) h += Ar[c][d] * xg[d];
      h = (h >= 0.f) ? h : pa * h;
      h = (h - sm1[c]) * sc1[c] + sb1[c];
      H[((size_t)b * 6 + c) * 512 + col] = __float2bfloat16(h);
    }
  }
}

// ---------------------------------------------------------------------------
// Per-batch: out(f32) = BN2(A @ hw + gb2)
// ---------------------------------------------------------------------------
__global__ void batch_out_kernel(const float* __restrict__ Afull, const bf16* __restrict__ HW,
                                 const float* __restrict__ gb2,
                                 const float* __restrict__ g2, const float* __restrict__ b2,
                                 const float* __restrict__ m2, const float* __restrict__ v2,
                                 float* __restrict__ out) {
  int b = blockIdx.x, tid = threadIdx.x;  // 64 threads
  __shared__ float Ar[36];
  __shared__ float sc[6], sm[6], sb[6];
  if (tid < 36) Ar[tid] = Afull[(size_t)b * 36 + tid];
  if (tid < 6) {
    sc[tid] = g2[tid] * rsqrtf(v2[tid] + 1e-5f);
    sm[tid] = m2[tid];
    sb[tid] = b2[tid];
  }
  __syncthreads();
  for (int col = tid; col < 256; col += 64) {
    float hw[6];
#pragma unroll
    for (int d = 0; d < 6; ++d) hw[d] = s2f(((const short*)HW)[((size_t)b * 6 + d) * 256 + col]);
    float gv = gb2[col];
#pragma unroll
    for (int c = 0; c < 6; ++c) {
      float o = gv;
#pragma unroll
      for (int d = 0; d < 6; ++d) o += Ar[c * 6 + d] * hw[d];
      o = (o - sm[c]) * sc[c] + sb[c];
      out[((size_t)b * 6 + c) * 256 + col] = o;
    }
  }
}

// ---------------------------------------------------------------------------
extern "C" void kernel_launch(void* const* d_in, const int* in_sizes, int n_in,
                              void* d_out, int out_size, void* d_ws, size_t ws_size,
                              hipStream_t stream) {
  const float* x    = (const float*)d_in[0];
  const float* aW1  = (const float*)d_in[1];
  const float* ab1  = (const float*)d_in[2];
  const float* aW2  = (const float*)d_in[3];
  const float* ab2  = (const float*)d_in[4];
  const float* linW = (const float*)d_in[5];
  const float* linb = (const float*)d_in[6];
  const float* gW1  = (const float*)d_in[7];
  const float* gb1  = (const float*)d_in[8];
  const float* gW2  = (const float*)d_in[9];
  const float* gb2  = (const float*)d_in[10];
  const float* prelu = (const float*)d_in[11];
  const float* bn1g = (const float*)d_in[12];
  const float* bn1b = (const float*)d_in[13];
  const float* bn1m = (const float*)d_in[14];
  const float* bn1v = (const float*)d_in[15];
  const float* bn2g = (const float*)d_in[16];
  const float* bn2b = (const float*)d_in[17];
  const float* bn2m = (const float*)d_in[18];
  const float* bn2v = (const float*)d_in[19];

  char* ws = (char*)d_ws;
  // layout (bytes): base 65.7 MB; +50.3 MB Xb if ws allows
  bf16* W1T  = (bf16*)(ws + 0);          // 5 x 512 x 1024
  bf16* W2T  = (bf16*)(ws + 5242880);    // 5 x 512 x 1024
  bf16* G1T  = (bf16*)(ws + 10485760);   // 512 x 1024
  bf16* G2T  = (bf16*)(ws + 11534336);   // 256 x 512
  float* S   = (float*)(ws + 11796480);  // 4096 x 5 x 36
  float* Af  = (float*)(ws + 14745600);  // 4096 x 36
  bf16* BufA = (bf16*)(ws + 15335424);   // 24576 x 512: Q, then XG, then HW
  bf16* BufB = (bf16*)(ws + 40501248);   // 24576 x 512: KV, then H
  bf16* Xb   = (bf16*)(ws + 65667072);   // 24576 x 1024 (optional)
  const bool big = ws_size >= 115998720ull;

  dim3 tb(32, 8);
  transpose_f2b<<<dim3(32, 16, 5), tb, 0, stream>>>(aW1, W1T, 1024, 512);
  transpose_f2b<<<dim3(32, 16, 5), tb, 0, stream>>>(aW2, W2T, 1024, 512);
  transpose_f2b<<<dim3(32, 16, 1), tb, 0, stream>>>(gW1, G1T, 1024, 512);
  transpose_f2b<<<dim3(16, 8, 1),  tb, 0, stream>>>(gW2, G2T, 512, 256);
  if (big) cvt_f32_bf16<<<12288, 256, 0, stream>>>(x, Xb, 3145728);

  // per head: Q,KV GEMM (z=2) then scores
  for (int k = 0; k < 5; ++k) {
    const bf16* w1 = W1T + (size_t)k * 512 * 1024;
    const bf16* w2 = W2T + (size_t)k * 512 * 1024;
    if (big)
      gemm_bt<0><<<dim3(192, 4, 2), 256, 0, stream>>>(
          Xb, w1, w2, ab1, ab2, k * 512, BufA, BufB, 24576, 512, 1024);
    else
      gemm_bt<1><<<dim3(192, 4, 2), 256, 0, stream>>>(
          x, w1, w2, ab1, ab2, k * 512, BufA, BufB, 24576, 512, 1024);
    scores_mfma<<<512, 256, 0, stream>>>(BufA, BufB, S, k);
  }

  // XG = X @ gW1 (Q dead -> BufA)
  if (big)
    gemm_bt<0><<<dim3(192, 4, 1), 256, 0, stream>>>(
        Xb, G1T, G1T, nullptr, nullptr, 0, BufA, BufA, 24576, 512, 1024);
  else
    gemm_bt<1><<<dim3(192, 4, 1), 256, 0, stream>>>(
        x, G1T, G1T, nullptr, nullptr, 0, BufA, BufA, 24576, 512, 1024);

  // softmaxes + A + H (KV dead -> H into BufB)
  batch_mid_kernel<<<4096, 64, 0, stream>>>(S, BufA, linW, linb, gb1, prelu,
                                            bn1g, bn1b, bn1m, bn1v, Af, BufB);

  // HW = H @ gW2 (XG dead -> HW into BufA)
  gemm_bt<0><<<dim3(192, 2, 1), 256, 0, stream>>>(
      BufB, G2T, G2T, nullptr, nullptr, 0, BufA, BufA, 24576, 256, 512);

  batch_out_kernel<<<4096, 64, 0, stream>>>(Af, BufA, gb2, bn2g, bn2b, bn2m, bn2v,
                                            (float*)d_out);
}